// Round 4
// baseline (73.672 us; speedup 1.0000x reference)
//
#include <hip/hip_runtime.h>

#define B_GRAPHS 64
#define MPG 32
#define TPG 8192
#define NM 2048
#define NT 524288
#define NL 65536
#define H 64
#define DT 18
#define DM 8

// ---------------------------------------------------------------------------
// K_side: machines encoder + weight folding (small, isolated so its register
// pressure doesn't cap the task kernel).
//   blocks [0,64)   : machine encoder + contrib (256 thr)
//   blocks [64,128) : weight folding            (64 active thr)
// ---------------------------------------------------------------------------
__global__ __launch_bounds__(256) void k_side(
    const float* __restrict__ xm,
    const float* __restrict__ m_ln_g, const float* __restrict__ m_ln_b,
    const float* __restrict__ m_w1, const float* __restrict__ m_b1,
    const float* __restrict__ m_w2, const float* __restrict__ m_b2,
    const float* __restrict__ lg_w1,
    const float* __restrict__ t_w2, const float* __restrict__ lg_w2,
    const float* __restrict__ o_w1, const float* __restrict__ t_b2,
    const float* __restrict__ lg_b1, const float* __restrict__ lg_b2,
    const float* __restrict__ o_b1,
    float* __restrict__ mh,              // [2048][64]
    float* __restrict__ mh_contrib,      // [2049][64]
    float* __restrict__ W_comb, float* __restrict__ W2comb,
    float* __restrict__ biasA, float* __restrict__ bias2)
{
    __shared__ float s_h[4][64];
    __shared__ float s_m[4][64];
    int tid = threadIdx.x, lane = tid & 63, wv = tid >> 6;
    int bid = blockIdx.x;

    if (bid < 64) {
        if (bid == 0 && tid < 64) mh_contrib[(long)NM * H + tid] = 0.0f;

        float w1r[DM];
#pragma unroll
        for (int i = 0; i < DM; i++) w1r[i] = m_w1[i * H + lane];
        float w2r[H];
#pragma unroll
        for (int i = 0; i < H; i++) w2r[i] = m_w2[i * H + lane];
        float Cr[H];
#pragma unroll
        for (int i = 0; i < H; i++) Cr[i] = lg_w1[(2 * H + i) * H + lane];
        float b1 = m_b1[lane], b2 = m_b2[lane];
        float g0[DM], bb[DM];
#pragma unroll
        for (int i = 0; i < DM; i++) { g0[i] = m_ln_g[i]; bb[i] = m_ln_b[i]; }

        int W = bid * 4 + wv;
        for (int k = 0; k < 8; k++) {
            int m = W * 8 + k;
            float x[DM];
#pragma unroll
            for (int i = 0; i < DM; i++) x[i] = xm[m * DM + i];
            float mu = 0.0f;
#pragma unroll
            for (int i = 0; i < DM; i++) mu += x[i];
            mu *= (1.0f / DM);
            float var = 0.0f;
#pragma unroll
            for (int i = 0; i < DM; i++) { float d = x[i] - mu; var += d * d; }
            var *= (1.0f / DM);
            float rs = rsqrtf(var + 1e-5f);
            float h = b1;
#pragma unroll
            for (int i = 0; i < DM; i++) {
                float xn = (x[i] - mu) * rs * g0[i] + bb[i];
                h = fmaf(xn, w1r[i], h);
            }
            h = fmaxf(h, 0.0f);
            __syncthreads();
            s_h[wv][lane] = h;
            __syncthreads();
            float o = b2;
#pragma unroll
            for (int i = 0; i < H; i++) o = fmaf(s_h[wv][i], w2r[i], o);
            __syncthreads();
            s_m[wv][lane] = o;
            __syncthreads();
            float c = 0.0f;
#pragma unroll
            for (int i = 0; i < H; i++) c = fmaf(s_m[wv][i], Cr[i], c);
            mh[(long)m * H + lane] = o;
            mh_contrib[(long)m * H + lane] = c;
        }
    } else {
        int i = bid - 64, j = tid;
        if (j < 64) {
            float a = 0.0f, b = 0.0f;
            for (int k = 0; k < H; k++) {
                a = fmaf(t_w2[i * H + k],  lg_w1[k * H + j], a);
                b = fmaf(lg_w2[i * H + k], o_w1[k * H + j], b);
            }
            W_comb[i * H + j] = a;
            W2comb[i * H + j] = b;
            if (i == 0) {
                float ba = lg_b1[j], b2v = o_b1[j];
                for (int k = 0; k < H; k++) {
                    ba  = fmaf(t_b2[k],  lg_w1[k * H + j], ba);
                    b2v = fmaf(lg_b2[k], o_w1[k * H + j], b2v);
                }
                biasA[j] = ba;
                bias2[j] = b2v;
            }
        }
    }
}

// ---------------------------------------------------------------------------
// K2 v2: task relu-sum, lane-parallel LDS + scalar weights.
// 512 blocks x 256 thr; block owns rows [bid*1024, +1024) in 4 tiles of 256.
// Per tile: thread LNs its own row in registers, writes TRANSPOSED
// s_xt[dim][row] (stride-1 across lanes). Compute: wave w owns output dims
// [w*16, w*16+16); lane l owns rows 4l..4l+3 via lane-parallel ds_read_b128.
// Weights t_w1 are wave-uniform -> readfirstlane forces s_load (SMEM pipe).
// ---------------------------------------------------------------------------
__global__ __launch_bounds__(256) void k_tasks2(
    const float* __restrict__ xt,
    const float* __restrict__ t_ln_g, const float* __restrict__ t_ln_b,
    const float* __restrict__ t_w1, const float* __restrict__ t_b1,
    float* __restrict__ t_sum_partial,   // [512][64]
    float* __restrict__ t_cnt_partial)   // [512]
{
    __shared__ float s_xt[DT * 256];     // 18 KB transposed [dim][row]
    __shared__ float s_red[4][64][17];   // 17.4 KB, padded
    int tid = threadIdx.x, lane = tid & 63, w = tid >> 6;
    int wb = __builtin_amdgcn_readfirstlane(w * 16);
    long base = (long)blockIdx.x * 1024;

    float bs[16];
#pragma unroll
    for (int k = 0; k < 16; k++) bs[k] = t_b1[wb + k];

    float acc[16];
#pragma unroll
    for (int k = 0; k < 16; k++) acc[k] = 0.0f;

#pragma unroll 1
    for (int tile = 0; tile < 4; tile++) {
        // ---- load own row (72B stride, float2-aligned), LN in registers ----
        const float* rp = xt + (base + tile * 256 + tid) * DT;
        float xv[DT];
#pragma unroll
        for (int q = 0; q < 9; q++) {
            float2 v = *(const float2*)(rp + 2 * q);
            xv[2 * q] = v.x; xv[2 * q + 1] = v.y;
        }
        float mu = 0.0f;
#pragma unroll
        for (int i = 0; i < DT; i++) mu += xv[i];
        mu *= (1.0f / DT);
        float var = 0.0f;
#pragma unroll
        for (int i = 0; i < DT; i++) { float d = xv[i] - mu; var += d * d; }
        var *= (1.0f / DT);
        float rs = rsqrtf(var + 1e-5f);
        float xn[DT];
#pragma unroll
        for (int i = 0; i < DT; i++) xn[i] = (xv[i] - mu) * rs * t_ln_g[i] + t_ln_b[i];

        __syncthreads();                 // WAR vs previous tile's reads
#pragma unroll
        for (int i = 0; i < DT; i++) s_xt[i * 256 + tid] = xn[i];
        __syncthreads();                 // RAW

        // ---- compute: 4 rows x 16 dims per thread ----
        float h[4][16];
#pragma unroll
        for (int r = 0; r < 4; r++)
#pragma unroll
            for (int k = 0; k < 16; k++) h[r][k] = bs[k];

#pragma unroll
        for (int i = 0; i < DT; i++) {
            float4 xr = *(const float4*)(s_xt + i * 256 + 4 * lane);
            const float4* wp = (const float4*)(t_w1 + (i << 6) + wb);
            float4 wA = wp[0], wB = wp[1], wC = wp[2], wD = wp[3];
            float wv_[16] = {wA.x, wA.y, wA.z, wA.w, wB.x, wB.y, wB.z, wB.w,
                             wC.x, wC.y, wC.z, wC.w, wD.x, wD.y, wD.z, wD.w};
            float xr_[4] = {xr.x, xr.y, xr.z, xr.w};
#pragma unroll
            for (int r = 0; r < 4; r++)
#pragma unroll
                for (int k = 0; k < 16; k++)
                    h[r][k] = fmaf(xr_[r], wv_[k], h[r][k]);
        }
#pragma unroll
        for (int k = 0; k < 16; k++)
            acc[k] += (fmaxf(h[0][k], 0.0f) + fmaxf(h[1][k], 0.0f))
                    + (fmaxf(h[2][k], 0.0f) + fmaxf(h[3][k], 0.0f));
    }

    // ---- reduce acc across lanes ----
    __syncthreads();
#pragma unroll
    for (int k = 0; k < 16; k++) s_red[w][lane][k] = acc[k];
    __syncthreads();
    if (tid < 64) {
        int wi = tid >> 4, k = tid & 15;
        float s = 0.0f;
        for (int l = 0; l < 64; l++) s += s_red[wi][l][k];
        t_sum_partial[blockIdx.x * 64 + tid] = s;
    }
    if (tid == 0) t_cnt_partial[blockIdx.x] = 1024.0f;
}

// ---------------------------------------------------------------------------
// K3: per-graph aggregation.  64 blocks (one per graph) x 64 threads.
// ---------------------------------------------------------------------------
__global__ __launch_bounds__(64) void k_graph(
    const float* __restrict__ t_sum_partial, const float* __restrict__ t_cnt_partial,
    const float* __restrict__ mh, const int* __restrict__ mbatch,
    const float* __restrict__ t_w2, const float* __restrict__ t_b2,
    const float* __restrict__ a_w1, const float* __restrict__ a_b1,
    const float* __restrict__ a_w2, const float* __restrict__ a_b2,
    const float* __restrict__ lg_w1, const float* __restrict__ biasA,
    float* __restrict__ aggr_contrib, int* __restrict__ cum)
{
    int g = blockIdx.x, j = threadIdx.x;
    __shared__ float rs_[64], tm[64], mm[64], ah[64], ag[64];
    __shared__ float s_tcnt;
    __shared__ int s_lt[64], s_eq[64];

    float s = 0.0f;
    for (int p = 0; p < 8; p++) s += t_sum_partial[(g * 8 + p) * 64 + j];
    rs_[j] = s;
    if (j == 0) {
        float c = 0.0f;
        for (int p = 0; p < 8; p++) c += t_cnt_partial[g * 8 + p];
        s_tcnt = c;
    }
    int clt = 0, ceq = 0;
    for (int k = 0; k < 32; k++) {
        int bt = mbatch[j * 32 + k];
        clt += (bt < g) ? 1 : 0;
        ceq += (bt == g) ? 1 : 0;
    }
    s_lt[j] = clt; s_eq[j] = ceq;
    float msum = 0.0f;
    for (int k = 0; k < MPG; k++) msum += mh[(long)(g * MPG + k) * H + j];
    __syncthreads();

    int cum_g = 0, mcnt = 0;
    for (int k = 0; k < 64; k++) { cum_g += s_lt[k]; mcnt += s_eq[k]; }
    if (j == 0) cum[g] = cum_g;

    float tcnt = s_tcnt;
    float dot = 0.0f;
    for (int i = 0; i < H; i++) dot = fmaf(rs_[i], t_w2[i * H + j], dot);
    tm[j] = (dot + tcnt * t_b2[j]) / fmaxf(tcnt, 1.0f);
    mm[j] = msum / fmaxf((float)mcnt, 1.0f);
    __syncthreads();

    float h = a_b1[j];
    for (int i = 0; i < H; i++) h = fmaf(tm[i], a_w1[i * H + j], h);
    for (int i = 0; i < H; i++) h = fmaf(mm[i], a_w1[(H + i) * H + j], h);
    ah[j] = fmaxf(h, 0.0f);
    __syncthreads();

    float o = a_b2[j];
    for (int i = 0; i < H; i++) o = fmaf(ah[i], a_w2[i * H + j], o);
    ag[j] = o;
    __syncthreads();

    float c = biasA[j];
    for (int i = 0; i < H; i++) c = fmaf(ag[i], lg_w1[(H + i) * H + j], c);
    aggr_contrib[g * H + j] = c;
}

// ---------------------------------------------------------------------------
// K4 v4: per-label fused head. 512 blocks x 512 thr, 128 labels/block.
// Wave w owns output dims [w*8, w*8+8); lane handles labels {lane, lane+64}.
// Activations in LDS [dim][label] (lane-parallel b32); ALL weights/biases via
// wave-uniform scalar loads from global (readfirstlane) -> SMEM pipe, no LDS
// weight staging at all. 33 KB LDS.
// ---------------------------------------------------------------------------
__global__ __launch_bounds__(512) void k_labels4(
    const float* __restrict__ xt, const int* __restrict__ tbatch,
    const int* __restrict__ lidx,
    const float* __restrict__ t_ln_g, const float* __restrict__ t_ln_b,
    const float* __restrict__ t_w1, const float* __restrict__ t_b1,
    const float* __restrict__ W_comb, const float* __restrict__ W2comb,
    const float* __restrict__ bias2,
    const float* __restrict__ o_w2, const float* __restrict__ o_b2,
    const float* __restrict__ aggr_contrib, const float* __restrict__ mh_contrib,
    const int* __restrict__ cum,
    float* __restrict__ out)
{
    __shared__ float s_act[H * 128];      // 32 KB [dim][label]
    __shared__ int   s_gi[128], s_mi[128], s_t[128];

    int tid = threadIdx.x, lane = tid & 63, w = tid >> 6;
    int wb = __builtin_amdgcn_readfirstlane(w * 8);

    if (tid < 128) {
        int t = lidx[blockIdx.x * 128 + tid];
        s_t[tid] = t;
        int g = tbatch[t];
        int assign = (int)xt[(long)t * DT];
        s_gi[tid] = g;
        s_mi[tid] = (assign < 0) ? NM : (assign + cum[g]);
    }
    __syncthreads();

    // feature gather: 2 threads per label, 9 floats each -> [dim][label]
    if (tid < 256) {
        int r = tid >> 1, hh = tid & 1;
        const float* src = xt + (long)s_t[r] * DT + hh * 9;
#pragma unroll
        for (int j = 0; j < 9; j++) s_act[(hh * 9 + j) * 128 + r] = src[j];
    }
    __syncthreads();

    // LayerNorm per label (tid<128); LN params via uniform scalar loads
    if (tid < 128) {
        float xv[DT];
#pragma unroll
        for (int i = 0; i < DT; i++) xv[i] = s_act[i * 128 + tid];
        float mu = 0.0f;
#pragma unroll
        for (int i = 0; i < DT; i++) mu += xv[i];
        mu *= (1.0f / DT);
        float var = 0.0f;
#pragma unroll
        for (int i = 0; i < DT; i++) { float d = xv[i] - mu; var += d * d; }
        var *= (1.0f / DT);
        float rs = rsqrtf(var + 1e-5f);
#pragma unroll
        for (int i = 0; i < DT; i++)
            s_act[i * 128 + tid] = (xv[i] - mu) * rs * t_ln_g[i] + t_ln_b[i];
    }
    __syncthreads();

    float acc0[8], acc1[8];

    // ---- L1: a1 = relu(xn @ t_w1 + b1), dims wb..wb+7 ----
#pragma unroll
    for (int k = 0; k < 8; k++) { acc0[k] = t_b1[wb + k]; acc1[k] = acc0[k]; }
#pragma unroll
    for (int i = 0; i < DT; i++) {
        float av0 = s_act[i * 128 + lane];
        float av1 = s_act[i * 128 + 64 + lane];
        const float4* wp = (const float4*)(t_w1 + (i << 6) + wb);
        float4 wA = wp[0], wB = wp[1];
        float wv_[8] = {wA.x, wA.y, wA.z, wA.w, wB.x, wB.y, wB.z, wB.w};
#pragma unroll
        for (int k = 0; k < 8; k++) {
            acc0[k] = fmaf(av0, wv_[k], acc0[k]);
            acc1[k] = fmaf(av1, wv_[k], acc1[k]);
        }
    }
    __syncthreads();
#pragma unroll
    for (int k = 0; k < 8; k++) {
        s_act[(wb + k) * 128 + lane]      = fmaxf(acc0[k], 0.0f);
        s_act[(wb + k) * 128 + 64 + lane] = fmaxf(acc1[k], 0.0f);
    }
    __syncthreads();

    // ---- L2: p1 = a1 @ W_comb + aggr_contrib[g] + mh_contrib[m] ----
    {
        int g0 = s_gi[lane],      m0 = s_mi[lane];
        int g1 = s_gi[64 + lane], m1 = s_mi[64 + lane];
        const float4* a0p = (const float4*)(aggr_contrib + g0 * H + wb);
        const float4* m0p = (const float4*)(mh_contrib + (long)m0 * H + wb);
        const float4* a1p = (const float4*)(aggr_contrib + g1 * H + wb);
        const float4* m1p = (const float4*)(mh_contrib + (long)m1 * H + wb);
        float4 aA = a0p[0], aB = a0p[1], mA = m0p[0], mB = m0p[1];
        float4 cA = a1p[0], cB = a1p[1], nA = m1p[0], nB = m1p[1];
        acc0[0] = aA.x + mA.x; acc0[1] = aA.y + mA.y; acc0[2] = aA.z + mA.z; acc0[3] = aA.w + mA.w;
        acc0[4] = aB.x + mB.x; acc0[5] = aB.y + mB.y; acc0[6] = aB.z + mB.z; acc0[7] = aB.w + mB.w;
        acc1[0] = cA.x + nA.x; acc1[1] = cA.y + nA.y; acc1[2] = cA.z + nA.z; acc1[3] = cA.w + nA.w;
        acc1[4] = cB.x + nB.x; acc1[5] = cB.y + nB.y; acc1[6] = cB.z + nB.z; acc1[7] = cB.w + nB.w;
    }
#pragma unroll 4
    for (int i = 0; i < H; i++) {
        float av0 = s_act[i * 128 + lane];
        float av1 = s_act[i * 128 + 64 + lane];
        const float4* wp = (const float4*)(W_comb + (i << 6) + wb);
        float4 wA = wp[0], wB = wp[1];
        float wv_[8] = {wA.x, wA.y, wA.z, wA.w, wB.x, wB.y, wB.z, wB.w};
#pragma unroll
        for (int k = 0; k < 8; k++) {
            acc0[k] = fmaf(av0, wv_[k], acc0[k]);
            acc1[k] = fmaf(av1, wv_[k], acc1[k]);
        }
    }
    __syncthreads();
#pragma unroll
    for (int k = 0; k < 8; k++) {
        s_act[(wb + k) * 128 + lane]      = fmaxf(acc0[k], 0.0f);
        s_act[(wb + k) * 128 + 64 + lane] = fmaxf(acc1[k], 0.0f);
    }
    __syncthreads();

    // ---- L3: p2 = hid @ W2comb + bias2 ----
#pragma unroll
    for (int k = 0; k < 8; k++) { acc0[k] = bias2[wb + k]; acc1[k] = acc0[k]; }
#pragma unroll 4
    for (int i = 0; i < H; i++) {
        float av0 = s_act[i * 128 + lane];
        float av1 = s_act[i * 128 + 64 + lane];
        const float4* wp = (const float4*)(W2comb + (i << 6) + wb);
        float4 wA = wp[0], wB = wp[1];
        float wv_[8] = {wA.x, wA.y, wA.z, wA.w, wB.x, wB.y, wB.z, wB.w};
#pragma unroll
        for (int k = 0; k < 8; k++) {
            acc0[k] = fmaf(av0, wv_[k], acc0[k]);
            acc1[k] = fmaf(av1, wv_[k], acc1[k]);
        }
    }

    // ---- final: partial dot with o_w2, reduce across 8 waves via LDS ----
    float r0 = 0.0f, r1 = 0.0f;
#pragma unroll
    for (int k = 0; k < 8; k++) {
        float wv2 = o_w2[wb + k];
        r0 = fmaf(fmaxf(acc0[k], 0.0f), wv2, r0);
        r1 = fmaf(fmaxf(acc1[k], 0.0f), wv2, r1);
    }
    __syncthreads();                       // all hid reads done; reuse s_act
    s_act[w * 128 + lane]      = r0;
    s_act[w * 128 + 64 + lane] = r1;
    __syncthreads();
    if (tid < 128) {
        float s = o_b2[0];
#pragma unroll
        for (int q = 0; q < 8; q++) s += s_act[q * 128 + tid];
        out[blockIdx.x * 128 + tid] = s;
    }
}

// ---------------------------------------------------------------------------
extern "C" void kernel_launch(void* const* d_in, const int* in_sizes, int n_in,
                              void* d_out, int out_size, void* d_ws, size_t ws_size,
                              hipStream_t stream)
{
    (void)n_in; (void)out_size; (void)ws_size;
    const float* x_tasks         = (const float*)d_in[0];
    const float* x_machines      = (const float*)d_in[1];
    const int*   x_tasks_batch   = (const int*)d_in[2];
    const int*   x_machines_batch= (const int*)d_in[3];
    const int*   task_label_idx  = (const int*)d_in[4];
    const float* t_ln_g = (const float*)d_in[5];
    const float* t_ln_b = (const float*)d_in[6];
    const float *m_ln_g, *m_ln_b, *t_w1, *t_b1, *t_w2, *t_b2;
    if (in_sizes[7] == DM) {
        m_ln_g = (const float*)d_in[7];  m_ln_b = (const float*)d_in[8];
        t_w1   = (const float*)d_in[9];  t_b1   = (const float*)d_in[10];
        t_w2   = (const float*)d_in[11]; t_b2   = (const float*)d_in[12];
    } else {
        t_w1   = (const float*)d_in[7];  t_b1   = (const float*)d_in[8];
        t_w2   = (const float*)d_in[9];  t_b2   = (const float*)d_in[10];
        m_ln_g = (const float*)d_in[11]; m_ln_b = (const float*)d_in[12];
    }
    const float* m_w1 = (const float*)d_in[13]; const float* m_b1 = (const float*)d_in[14];
    const float* m_w2 = (const float*)d_in[15]; const float* m_b2 = (const float*)d_in[16];
    const float* a_w1 = (const float*)d_in[17]; const float* a_b1 = (const float*)d_in[18];
    const float* a_w2 = (const float*)d_in[19]; const float* a_b2 = (const float*)d_in[20];
    const float* lg_w1= (const float*)d_in[21]; const float* lg_b1= (const float*)d_in[22];
    const float* lg_w2= (const float*)d_in[23]; const float* lg_b2= (const float*)d_in[24];
    const float* o_w1 = (const float*)d_in[25]; const float* o_b1 = (const float*)d_in[26];
    const float* o_w2 = (const float*)d_in[27]; const float* o_b2 = (const float*)d_in[28];

    float* ws = (float*)d_ws;
    float* mh_contrib    = ws;                  // 2049*64 = 131136
    float* mh_arr        = ws + 131136;         // 2048*64 = 131072
    float* t_sum_partial = ws + 262208;         // 512*64  = 32768
    float* t_cnt_partial = ws + 294976;         // 512
    float* W_comb        = ws + 295488;         // 4096
    float* W2comb        = ws + 299584;         // 4096
    float* biasA         = ws + 303680;         // 64
    float* bias2         = ws + 303744;         // 64
    float* aggr_contrib  = ws + 303808;         // 4096
    int*   cum           = (int*)(ws + 307904); // 64

    k_side<<<128, 256, 0, stream>>>(x_machines, m_ln_g, m_ln_b, m_w1, m_b1, m_w2, m_b2,
                                    lg_w1, t_w2, lg_w2, o_w1, t_b2, lg_b1, lg_b2, o_b1,
                                    mh_arr, mh_contrib, W_comb, W2comb, biasA, bias2);
    k_tasks2<<<512, 256, 0, stream>>>(x_tasks, t_ln_g, t_ln_b, t_w1, t_b1,
                                      t_sum_partial, t_cnt_partial);
    k_graph<<<64, 64, 0, stream>>>(t_sum_partial, t_cnt_partial, mh_arr, x_machines_batch,
                                   t_w2, t_b2, a_w1, a_b1, a_w2, a_b2, lg_w1, biasA,
                                   aggr_contrib, cum);
    k_labels4<<<512, 512, 0, stream>>>(x_tasks, x_tasks_batch, task_label_idx,
                                       t_ln_g, t_ln_b, t_w1, t_b1, W_comb, W2comb, bias2,
                                       o_w2, o_b2, aggr_contrib, mh_contrib, cum,
                                       (float*)d_out);
}

// Round 5
// 67.163 us; speedup vs baseline: 1.0969x; 1.0969x over previous
//
#include <hip/hip_runtime.h>

#define B_GRAPHS 64
#define MPG 32
#define TPG 8192
#define NM 2048
#define NT 524288
#define NL 65536
#define H 64
#define DT 18
#define DM 8

// ---------------------------------------------------------------------------
// K_A: merged independent work.
//   blocks [0,512)   : tasks relu-sum partials (lane-parallel LDS scheme)
//   blocks [512,576) : machine encoder + contrib (256 thr)
//   blocks [576,640) : weight folding            (64 active thr)
// ---------------------------------------------------------------------------
__global__ __launch_bounds__(256) void k_front(
    const float* __restrict__ xt,
    const float* __restrict__ t_ln_g, const float* __restrict__ t_ln_b,
    const float* __restrict__ t_w1, const float* __restrict__ t_b1,
    const float* __restrict__ xm,
    const float* __restrict__ m_ln_g, const float* __restrict__ m_ln_b,
    const float* __restrict__ m_w1, const float* __restrict__ m_b1,
    const float* __restrict__ m_w2, const float* __restrict__ m_b2,
    const float* __restrict__ lg_w1,
    const float* __restrict__ t_w2, const float* __restrict__ lg_w2,
    const float* __restrict__ o_w1, const float* __restrict__ t_b2,
    const float* __restrict__ lg_b1, const float* __restrict__ lg_b2,
    const float* __restrict__ o_b1,
    float* __restrict__ t_sum_partial,   // [512][64]
    float* __restrict__ t_cnt_partial,   // [512]
    float* __restrict__ mh,              // [2048][64]
    float* __restrict__ mh_contrib,      // [2049][64]
    float* __restrict__ W_comb, float* __restrict__ W2comb,
    float* __restrict__ biasA, float* __restrict__ bias2)
{
    __shared__ float s_xt[DT * 256];     // 18 KB transposed [dim][row]
    __shared__ float s_red2[4][64][17];  // 17.4 KB padded reduction buffer
    __shared__ float s_h[4][64];         // machines
    __shared__ float s_m[4][64];

    int tid = threadIdx.x, lane = tid & 63, w = tid >> 6;
    int bid = blockIdx.x;

    if (bid < 512) {
        // ---------------- tasks part (lane-parallel) ----------------
        int wb = __builtin_amdgcn_readfirstlane(w * 16);
        long base = (long)bid * 1024;

        float bs[16];
#pragma unroll
        for (int k = 0; k < 16; k++) bs[k] = t_b1[wb + k];

        float acc[16];
#pragma unroll
        for (int k = 0; k < 16; k++) acc[k] = 0.0f;

#pragma unroll 1
        for (int tile = 0; tile < 4; tile++) {
            // own row (72B stride, float2-aligned), LN in registers
            const float* rp = xt + (base + tile * 256 + tid) * DT;
            float xv[DT];
#pragma unroll
            for (int q = 0; q < 9; q++) {
                float2 v = *(const float2*)(rp + 2 * q);
                xv[2 * q] = v.x; xv[2 * q + 1] = v.y;
            }
            float mu = 0.0f;
#pragma unroll
            for (int i = 0; i < DT; i++) mu += xv[i];
            mu *= (1.0f / DT);
            float var = 0.0f;
#pragma unroll
            for (int i = 0; i < DT; i++) { float d = xv[i] - mu; var += d * d; }
            var *= (1.0f / DT);
            float rs = rsqrtf(var + 1e-5f);
            float xn[DT];
#pragma unroll
            for (int i = 0; i < DT; i++) xn[i] = (xv[i] - mu) * rs * t_ln_g[i] + t_ln_b[i];

            __syncthreads();             // WAR vs previous tile's reads
#pragma unroll
            for (int i = 0; i < DT; i++) s_xt[i * 256 + tid] = xn[i];
            __syncthreads();             // RAW

            // compute: lane owns rows 4*lane..4*lane+3; wave owns dims wb..wb+15
            float h[4][16];
#pragma unroll
            for (int r = 0; r < 4; r++)
#pragma unroll
                for (int k = 0; k < 16; k++) h[r][k] = bs[k];

#pragma unroll
            for (int i = 0; i < DT; i++) {
                float4 xr = *(const float4*)(s_xt + i * 256 + 4 * lane);
                const float4* wp = (const float4*)(t_w1 + (i << 6) + wb);
                float4 wA = wp[0], wB = wp[1], wC = wp[2], wD = wp[3];
                float wv_[16] = {wA.x, wA.y, wA.z, wA.w, wB.x, wB.y, wB.z, wB.w,
                                 wC.x, wC.y, wC.z, wC.w, wD.x, wD.y, wD.z, wD.w};
                float xr_[4] = {xr.x, xr.y, xr.z, xr.w};
#pragma unroll
                for (int r = 0; r < 4; r++)
#pragma unroll
                    for (int k = 0; k < 16; k++)
                        h[r][k] = fmaf(xr_[r], wv_[k], h[r][k]);
            }
#pragma unroll
            for (int k = 0; k < 16; k++)
                acc[k] += (fmaxf(h[0][k], 0.0f) + fmaxf(h[1][k], 0.0f))
                        + (fmaxf(h[2][k], 0.0f) + fmaxf(h[3][k], 0.0f));
        }

        // reduce acc across lanes
        __syncthreads();
#pragma unroll
        for (int k = 0; k < 16; k++) s_red2[w][lane][k] = acc[k];
        __syncthreads();
        if (tid < 64) {
            int wi = tid >> 4, k = tid & 15;
            float s = 0.0f;
            for (int l = 0; l < 64; l++) s += s_red2[wi][l][k];
            t_sum_partial[bid * 64 + tid] = s;
        }
        if (tid == 0) t_cnt_partial[bid] = 1024.0f;

    } else if (bid < 576) {
        // ---------------- machines part ----------------
        int mbid = bid - 512;
        if (mbid == 0 && tid < 64) mh_contrib[(long)NM * H + tid] = 0.0f;

        float w1r[DM];
#pragma unroll
        for (int i = 0; i < DM; i++) w1r[i] = m_w1[i * H + lane];
        float w2r[H];
#pragma unroll
        for (int i = 0; i < H; i++) w2r[i] = m_w2[i * H + lane];
        float Cr[H];
#pragma unroll
        for (int i = 0; i < H; i++) Cr[i] = lg_w1[(2 * H + i) * H + lane];
        float b1 = m_b1[lane], b2 = m_b2[lane];
        float g0[DM], bb[DM];
#pragma unroll
        for (int i = 0; i < DM; i++) { g0[i] = m_ln_g[i]; bb[i] = m_ln_b[i]; }

        int W = mbid * 4 + w;
        for (int k = 0; k < 8; k++) {
            int m = W * 8 + k;
            float x[DM];
#pragma unroll
            for (int i = 0; i < DM; i++) x[i] = xm[m * DM + i];
            float mu = 0.0f;
#pragma unroll
            for (int i = 0; i < DM; i++) mu += x[i];
            mu *= (1.0f / DM);
            float var = 0.0f;
#pragma unroll
            for (int i = 0; i < DM; i++) { float d = x[i] - mu; var += d * d; }
            var *= (1.0f / DM);
            float rs = rsqrtf(var + 1e-5f);
            float h = b1;
#pragma unroll
            for (int i = 0; i < DM; i++) {
                float xn = (x[i] - mu) * rs * g0[i] + bb[i];
                h = fmaf(xn, w1r[i], h);
            }
            h = fmaxf(h, 0.0f);
            __syncthreads();
            s_h[w][lane] = h;
            __syncthreads();
            float o = b2;
#pragma unroll
            for (int i = 0; i < H; i++) o = fmaf(s_h[w][i], w2r[i], o);
            __syncthreads();
            s_m[w][lane] = o;
            __syncthreads();
            float c = 0.0f;
#pragma unroll
            for (int i = 0; i < H; i++) c = fmaf(s_m[w][i], Cr[i], c);
            mh[(long)m * H + lane] = o;
            mh_contrib[(long)m * H + lane] = c;
        }
    } else {
        // ---------------- fold part ----------------
        int i = bid - 576, j = tid;
        if (j < 64) {
            float a = 0.0f, b = 0.0f;
            for (int k = 0; k < H; k++) {
                a = fmaf(t_w2[i * H + k],  lg_w1[k * H + j], a);
                b = fmaf(lg_w2[i * H + k], o_w1[k * H + j], b);
            }
            W_comb[i * H + j] = a;
            W2comb[i * H + j] = b;
            if (i == 0) {
                float ba = lg_b1[j], b2v = o_b1[j];
                for (int k = 0; k < H; k++) {
                    ba  = fmaf(t_b2[k],  lg_w1[k * H + j], ba);
                    b2v = fmaf(lg_b2[k], o_w1[k * H + j], b2v);
                }
                biasA[j] = ba;
                bias2[j] = b2v;
            }
        }
    }
}

// ---------------------------------------------------------------------------
// K3: per-graph aggregation.  64 blocks (one per graph) x 64 threads.
// ---------------------------------------------------------------------------
__global__ __launch_bounds__(64) void k_graph(
    const float* __restrict__ t_sum_partial, const float* __restrict__ t_cnt_partial,
    const float* __restrict__ mh, const int* __restrict__ mbatch,
    const float* __restrict__ t_w2, const float* __restrict__ t_b2,
    const float* __restrict__ a_w1, const float* __restrict__ a_b1,
    const float* __restrict__ a_w2, const float* __restrict__ a_b2,
    const float* __restrict__ lg_w1, const float* __restrict__ biasA,
    float* __restrict__ aggr_contrib, int* __restrict__ cum)
{
    int g = blockIdx.x, j = threadIdx.x;
    __shared__ float rs_[64], tm[64], mm[64], ah[64], ag[64];
    __shared__ float s_tcnt;
    __shared__ int s_lt[64], s_eq[64];

    float s = 0.0f;
    for (int p = 0; p < 8; p++) s += t_sum_partial[(g * 8 + p) * 64 + j];
    rs_[j] = s;
    if (j == 0) {
        float c = 0.0f;
        for (int p = 0; p < 8; p++) c += t_cnt_partial[g * 8 + p];
        s_tcnt = c;
    }
    int clt = 0, ceq = 0;
    for (int k = 0; k < 32; k++) {
        int bt = mbatch[j * 32 + k];
        clt += (bt < g) ? 1 : 0;
        ceq += (bt == g) ? 1 : 0;
    }
    s_lt[j] = clt; s_eq[j] = ceq;
    float msum = 0.0f;
    for (int k = 0; k < MPG; k++) msum += mh[(long)(g * MPG + k) * H + j];
    __syncthreads();

    int cum_g = 0, mcnt = 0;
    for (int k = 0; k < 64; k++) { cum_g += s_lt[k]; mcnt += s_eq[k]; }
    if (j == 0) cum[g] = cum_g;

    float tcnt = s_tcnt;
    float dot = 0.0f;
    for (int i = 0; i < H; i++) dot = fmaf(rs_[i], t_w2[i * H + j], dot);
    tm[j] = (dot + tcnt * t_b2[j]) / fmaxf(tcnt, 1.0f);
    mm[j] = msum / fmaxf((float)mcnt, 1.0f);
    __syncthreads();

    float h = a_b1[j];
    for (int i = 0; i < H; i++) h = fmaf(tm[i], a_w1[i * H + j], h);
    for (int i = 0; i < H; i++) h = fmaf(mm[i], a_w1[(H + i) * H + j], h);
    ah[j] = fmaxf(h, 0.0f);
    __syncthreads();

    float o = a_b2[j];
    for (int i = 0; i < H; i++) o = fmaf(ah[i], a_w2[i * H + j], o);
    ag[j] = o;
    __syncthreads();

    float c = biasA[j];
    for (int i = 0; i < H; i++) c = fmaf(ag[i], lg_w1[(H + i) * H + j], c);
    aggr_contrib[g * H + j] = c;
}

// ---------------------------------------------------------------------------
// K4 v3 (round-3 version, restored verbatim): per-label fused head.
// 512 blocks x 512 threads; block handles 128 labels. Wave w (0..7) owns
// output dims w*8..w*8+7; lane handles labels {lane, lane+64}. Activations
// in LDS [dim][label]; weights LDS-staged, broadcast b128.
// ---------------------------------------------------------------------------
__global__ __launch_bounds__(512) void k_labels3(
    const float* __restrict__ xt, const int* __restrict__ tbatch,
    const int* __restrict__ lidx,
    const float* __restrict__ t_ln_g, const float* __restrict__ t_ln_b,
    const float* __restrict__ t_w1, const float* __restrict__ t_b1,
    const float* __restrict__ W_comb, const float* __restrict__ W2comb,
    const float* __restrict__ bias2,
    const float* __restrict__ o_w2, const float* __restrict__ o_b2,
    const float* __restrict__ aggr_contrib, const float* __restrict__ mh_contrib,
    const int* __restrict__ cum,
    float* __restrict__ out)
{
    __shared__ float s_act[H * 128];      // 32 KB [dim][label]
    __shared__ float s_w1[DT * H];        // 4.5 KB
    __shared__ float s_Wc[H * H];         // 16 KB
    __shared__ float s_W2[H * H];         // 16 KB
    __shared__ float s_b1v[H], s_b2v[H], s_ow2[H];
    __shared__ float s_lng[DT], s_lnb[DT];
    __shared__ int   s_gi[128], s_mi[128], s_t[128];
    __shared__ float s_ob2v;

    int tid = threadIdx.x, lane = tid & 63, w = tid >> 6;   // w in 0..7
    int wb = w * 8;

    for (int i = tid; i < DT * H; i += 512) s_w1[i] = t_w1[i];
    for (int i = tid; i < H * H; i += 512) { s_Wc[i] = W_comb[i]; s_W2[i] = W2comb[i]; }
    if (tid < H) { s_b1v[tid] = t_b1[tid]; s_b2v[tid] = bias2[tid]; s_ow2[tid] = o_w2[tid]; }
    if (tid < DT) { s_lng[tid] = t_ln_g[tid]; s_lnb[tid] = t_ln_b[tid]; }
    if (tid == 0) s_ob2v = o_b2[0];
    if (tid < 128) {
        int t = lidx[blockIdx.x * 128 + tid];
        s_t[tid] = t;
        int g = tbatch[t];
        int assign = (int)xt[(long)t * DT];
        s_gi[tid] = g;
        s_mi[tid] = (assign < 0) ? NM : (assign + cum[g]);
    }
    __syncthreads();

    // feature gather: 2 threads per label, 9 floats each -> [dim][label]
    if (tid < 256) {
        int r = tid >> 1, hh = tid & 1;
        const float* src = xt + (long)s_t[r] * DT + hh * 9;
#pragma unroll
        for (int j = 0; j < 9; j++) s_act[(hh * 9 + j) * 128 + r] = src[j];
    }
    __syncthreads();

    // LayerNorm per label (tid<128), columns are thread-private
    if (tid < 128) {
        float xv[DT];
#pragma unroll
        for (int i = 0; i < DT; i++) xv[i] = s_act[i * 128 + tid];
        float mu = 0.0f;
#pragma unroll
        for (int i = 0; i < DT; i++) mu += xv[i];
        mu *= (1.0f / DT);
        float var = 0.0f;
#pragma unroll
        for (int i = 0; i < DT; i++) { float d = xv[i] - mu; var += d * d; }
        var *= (1.0f / DT);
        float rs = rsqrtf(var + 1e-5f);
#pragma unroll
        for (int i = 0; i < DT; i++)
            s_act[i * 128 + tid] = (xv[i] - mu) * rs * s_lng[i] + s_lnb[i];
    }
    __syncthreads();

    float acc0[8], acc1[8];

    // ---- L1: a1 = relu(xn @ t_w1 + b1), dims wb..wb+7 ----
#pragma unroll
    for (int k = 0; k < 8; k++) { acc0[k] = s_b1v[wb + k]; acc1[k] = acc0[k]; }
    for (int i = 0; i < DT; i++) {
        float av0 = s_act[i * 128 + lane];
        float av1 = s_act[i * 128 + 64 + lane];
        const float4* wp = (const float4*)(s_w1 + i * H + wb);
        float4 wA = wp[0], wB = wp[1];
        acc0[0] = fmaf(av0, wA.x, acc0[0]); acc1[0] = fmaf(av1, wA.x, acc1[0]);
        acc0[1] = fmaf(av0, wA.y, acc0[1]); acc1[1] = fmaf(av1, wA.y, acc1[1]);
        acc0[2] = fmaf(av0, wA.z, acc0[2]); acc1[2] = fmaf(av1, wA.z, acc1[2]);
        acc0[3] = fmaf(av0, wA.w, acc0[3]); acc1[3] = fmaf(av1, wA.w, acc1[3]);
        acc0[4] = fmaf(av0, wB.x, acc0[4]); acc1[4] = fmaf(av1, wB.x, acc1[4]);
        acc0[5] = fmaf(av0, wB.y, acc0[5]); acc1[5] = fmaf(av1, wB.y, acc1[5]);
        acc0[6] = fmaf(av0, wB.z, acc0[6]); acc1[6] = fmaf(av1, wB.z, acc1[6]);
        acc0[7] = fmaf(av0, wB.w, acc0[7]); acc1[7] = fmaf(av1, wB.w, acc1[7]);
    }
    __syncthreads();                       // all xn reads done
#pragma unroll
    for (int k = 0; k < 8; k++) {
        s_act[(wb + k) * 128 + lane]      = fmaxf(acc0[k], 0.0f);
        s_act[(wb + k) * 128 + 64 + lane] = fmaxf(acc1[k], 0.0f);
    }
    __syncthreads();

    // ---- L2: p1 = a1 @ W_comb + aggr_contrib[g] + mh_contrib[m] ----
    {
        int g0 = s_gi[lane],      m0 = s_mi[lane];
        int g1 = s_gi[64 + lane], m1 = s_mi[64 + lane];
        const float4* a0p = (const float4*)(aggr_contrib + g0 * H + wb);
        const float4* m0p = (const float4*)(mh_contrib + (long)m0 * H + wb);
        const float4* a1p = (const float4*)(aggr_contrib + g1 * H + wb);
        const float4* m1p = (const float4*)(mh_contrib + (long)m1 * H + wb);
        float4 aA = a0p[0], aB = a0p[1], mA = m0p[0], mB = m0p[1];
        float4 cA = a1p[0], cB = a1p[1], nA = m1p[0], nB = m1p[1];
        acc0[0] = aA.x + mA.x; acc0[1] = aA.y + mA.y; acc0[2] = aA.z + mA.z; acc0[3] = aA.w + mA.w;
        acc0[4] = aB.x + mB.x; acc0[5] = aB.y + mB.y; acc0[6] = aB.z + mB.z; acc0[7] = aB.w + mB.w;
        acc1[0] = cA.x + nA.x; acc1[1] = cA.y + nA.y; acc1[2] = cA.z + nA.z; acc1[3] = cA.w + nA.w;
        acc1[4] = cB.x + nB.x; acc1[5] = cB.y + nB.y; acc1[6] = cB.z + nB.z; acc1[7] = cB.w + nB.w;
    }
    for (int i = 0; i < H; i++) {
        float av0 = s_act[i * 128 + lane];
        float av1 = s_act[i * 128 + 64 + lane];
        const float4* wp = (const float4*)(s_Wc + i * H + wb);
        float4 wA = wp[0], wB = wp[1];
        acc0[0] = fmaf(av0, wA.x, acc0[0]); acc1[0] = fmaf(av1, wA.x, acc1[0]);
        acc0[1] = fmaf(av0, wA.y, acc0[1]); acc1[1] = fmaf(av1, wA.y, acc1[1]);
        acc0[2] = fmaf(av0, wA.z, acc0[2]); acc1[2] = fmaf(av1, wA.z, acc1[2]);
        acc0[3] = fmaf(av0, wA.w, acc0[3]); acc1[3] = fmaf(av1, wA.w, acc1[3]);
        acc0[4] = fmaf(av0, wB.x, acc0[4]); acc1[4] = fmaf(av1, wB.x, acc1[4]);
        acc0[5] = fmaf(av0, wB.y, acc0[5]); acc1[5] = fmaf(av1, wB.y, acc1[5]);
        acc0[6] = fmaf(av0, wB.z, acc0[6]); acc1[6] = fmaf(av1, wB.z, acc1[6]);
        acc0[7] = fmaf(av0, wB.w, acc0[7]); acc1[7] = fmaf(av1, wB.w, acc1[7]);
    }
    __syncthreads();                       // all a1 reads done
#pragma unroll
    for (int k = 0; k < 8; k++) {
        s_act[(wb + k) * 128 + lane]      = fmaxf(acc0[k], 0.0f);
        s_act[(wb + k) * 128 + 64 + lane] = fmaxf(acc1[k], 0.0f);
    }
    __syncthreads();

    // ---- L3: p2 = hid @ W2comb + bias2 ----
#pragma unroll
    for (int k = 0; k < 8; k++) { acc0[k] = s_b2v[wb + k]; acc1[k] = acc0[k]; }
    for (int i = 0; i < H; i++) {
        float av0 = s_act[i * 128 + lane];
        float av1 = s_act[i * 128 + 64 + lane];
        const float4* wp = (const float4*)(s_W2 + i * H + wb);
        float4 wA = wp[0], wB = wp[1];
        acc0[0] = fmaf(av0, wA.x, acc0[0]); acc1[0] = fmaf(av1, wA.x, acc1[0]);
        acc0[1] = fmaf(av0, wA.y, acc0[1]); acc1[1] = fmaf(av1, wA.y, acc1[1]);
        acc0[2] = fmaf(av0, wA.z, acc0[2]); acc1[2] = fmaf(av1, wA.z, acc1[2]);
        acc0[3] = fmaf(av0, wA.w, acc0[3]); acc1[3] = fmaf(av1, wA.w, acc1[3]);
        acc0[4] = fmaf(av0, wB.x, acc0[4]); acc1[4] = fmaf(av1, wB.x, acc1[4]);
        acc0[5] = fmaf(av0, wB.y, acc0[5]); acc1[5] = fmaf(av1, wB.y, acc1[5]);
        acc0[6] = fmaf(av0, wB.z, acc0[6]); acc1[6] = fmaf(av1, wB.z, acc1[6]);
        acc0[7] = fmaf(av0, wB.w, acc0[7]); acc1[7] = fmaf(av1, wB.w, acc1[7]);
    }

    // ---- final: partial dot with o_w2, reduce across 8 waves via LDS ----
    float r0 = 0.0f, r1 = 0.0f;
#pragma unroll
    for (int k = 0; k < 8; k++) {
        float wv2 = s_ow2[wb + k];
        r0 = fmaf(fmaxf(acc0[k], 0.0f), wv2, r0);
        r1 = fmaf(fmaxf(acc1[k], 0.0f), wv2, r1);
    }
    __syncthreads();                       // all hid reads done; reuse s_act rows 0..7
    s_act[w * 128 + lane]      = r0;
    s_act[w * 128 + 64 + lane] = r1;
    __syncthreads();
    if (tid < 128) {
        float s = s_ob2v;
#pragma unroll
        for (int q = 0; q < 8; q++) s += s_act[q * 128 + tid];
        out[blockIdx.x * 128 + tid] = s;
    }
}

// ---------------------------------------------------------------------------
extern "C" void kernel_launch(void* const* d_in, const int* in_sizes, int n_in,
                              void* d_out, int out_size, void* d_ws, size_t ws_size,
                              hipStream_t stream)
{
    (void)n_in; (void)out_size; (void)ws_size;
    const float* x_tasks         = (const float*)d_in[0];
    const float* x_machines      = (const float*)d_in[1];
    const int*   x_tasks_batch   = (const int*)d_in[2];
    const int*   x_machines_batch= (const int*)d_in[3];
    const int*   task_label_idx  = (const int*)d_in[4];
    const float* t_ln_g = (const float*)d_in[5];
    const float* t_ln_b = (const float*)d_in[6];
    const float *m_ln_g, *m_ln_b, *t_w1, *t_b1, *t_w2, *t_b2;
    if (in_sizes[7] == DM) {
        m_ln_g = (const float*)d_in[7];  m_ln_b = (const float*)d_in[8];
        t_w1   = (const float*)d_in[9];  t_b1   = (const float*)d_in[10];
        t_w2   = (const float*)d_in[11]; t_b2   = (const float*)d_in[12];
    } else {
        t_w1   = (const float*)d_in[7];  t_b1   = (const float*)d_in[8];
        t_w2   = (const float*)d_in[9];  t_b2   = (const float*)d_in[10];
        m_ln_g = (const float*)d_in[11]; m_ln_b = (const float*)d_in[12];
    }
    const float* m_w1 = (const float*)d_in[13]; const float* m_b1 = (const float*)d_in[14];
    const float* m_w2 = (const float*)d_in[15]; const float* m_b2 = (const float*)d_in[16];
    const float* a_w1 = (const float*)d_in[17]; const float* a_b1 = (const float*)d_in[18];
    const float* a_w2 = (const float*)d_in[19]; const float* a_b2 = (const float*)d_in[20];
    const float* lg_w1= (const float*)d_in[21]; const float* lg_b1= (const float*)d_in[22];
    const float* lg_w2= (const float*)d_in[23]; const float* lg_b2= (const float*)d_in[24];
    const float* o_w1 = (const float*)d_in[25]; const float* o_b1 = (const float*)d_in[26];
    const float* o_w2 = (const float*)d_in[27]; const float* o_b2 = (const float*)d_in[28];

    float* ws = (float*)d_ws;
    float* mh_contrib    = ws;                  // 2049*64 = 131136
    float* mh_arr        = ws + 131136;         // 2048*64 = 131072
    float* t_sum_partial = ws + 262208;         // 512*64  = 32768
    float* t_cnt_partial = ws + 294976;         // 512
    float* W_comb        = ws + 295488;         // 4096
    float* W2comb        = ws + 299584;         // 4096
    float* biasA         = ws + 303680;         // 64
    float* bias2         = ws + 303744;         // 64
    float* aggr_contrib  = ws + 303808;         // 4096
    int*   cum           = (int*)(ws + 307904); // 64

    k_front<<<640, 256, 0, stream>>>(x_tasks, t_ln_g, t_ln_b, t_w1, t_b1,
                                     x_machines, m_ln_g, m_ln_b, m_w1, m_b1, m_w2, m_b2,
                                     lg_w1, t_w2, lg_w2, o_w1, t_b2, lg_b1, lg_b2, o_b1,
                                     t_sum_partial, t_cnt_partial, mh_arr, mh_contrib,
                                     W_comb, W2comb, biasA, bias2);
    k_graph<<<64, 64, 0, stream>>>(t_sum_partial, t_cnt_partial, mh_arr, x_machines_batch,
                                   t_w2, t_b2, a_w1, a_b1, a_w2, a_b2, lg_w1, biasA,
                                   aggr_contrib, cum);
    k_labels3<<<512, 512, 0, stream>>>(x_tasks, x_tasks_batch, task_label_idx,
                                       t_ln_g, t_ln_b, t_w1, t_b1, W_comb, W2comb, bias2,
                                       o_w2, o_b2, aggr_contrib, mh_contrib, cum,
                                       (float*)d_out);
}

// Round 6
// 58.849 us; speedup vs baseline: 1.2519x; 1.1413x over previous
//
#include <hip/hip_runtime.h>

#define B_GRAPHS 64
#define MPG 32
#define TPG 8192
#define NM 2048
#define NT 524288
#define NL 65536
#define H 64
#define DT 18
#define DM 8

typedef __attribute__((ext_vector_type(8))) short bf8;
typedef __attribute__((ext_vector_type(4))) float f32x4;

__device__ __forceinline__ unsigned short f2bf(float f) {
    unsigned u = __builtin_bit_cast(unsigned, f);
    u += 0x7FFFu + ((u >> 16) & 1u);          // RNE
    return (unsigned short)(u >> 16);
}

// ---------------------------------------------------------------------------
// K_A: merged independent work.
//   blocks [0,512)   : tasks relu-sum partials — bf16 MFMA path
//   blocks [512,576) : machine encoder + contrib (256 thr)
//   blocks [576,640) : weight folding            (64 active thr)
// ---------------------------------------------------------------------------
__global__ __launch_bounds__(256) void k_front(
    const float* __restrict__ xt,
    const float* __restrict__ t_ln_g, const float* __restrict__ t_ln_b,
    const float* __restrict__ t_w1, const float* __restrict__ t_b1,
    const float* __restrict__ xm,
    const float* __restrict__ m_ln_g, const float* __restrict__ m_ln_b,
    const float* __restrict__ m_w1, const float* __restrict__ m_b1,
    const float* __restrict__ m_w2, const float* __restrict__ m_b2,
    const float* __restrict__ lg_w1,
    const float* __restrict__ t_w2, const float* __restrict__ lg_w2,
    const float* __restrict__ o_w1, const float* __restrict__ t_b2,
    const float* __restrict__ lg_b1, const float* __restrict__ lg_b2,
    const float* __restrict__ o_b1,
    float* __restrict__ t_sum_partial,   // [512][64]
    float* __restrict__ t_cnt_partial,   // [512]
    float* __restrict__ mh,              // [2048][64]
    float* __restrict__ mh_contrib,      // [2049][64]
    float* __restrict__ W_comb, float* __restrict__ W2comb,
    float* __restrict__ biasA, float* __restrict__ bias2)
{
    // tasks: 256 rows x 20 dwords (80B stride: 16 data dwords used, stride
    // 20 breaks the 64B power-of-2 bank pattern -> ~2-way conflicts)
    __shared__ unsigned int s_bf[256 * 20];          // 20 KB
    __shared__ float s_part[4][64];                  // per-wave col partials
    __shared__ float s_h[4][64];                     // machines
    __shared__ float s_m[4][64];

    int tid = threadIdx.x, lane = tid & 63, w = tid >> 6;
    int bid = blockIdx.x;

    if (bid < 512) {
        // ---------------- tasks part (MFMA) ----------------
        int col = lane & 15, grp = lane >> 4;
        long base = (long)bid * 1024;

        // B fragments: lane holds W1[k][t*16+col], k = grp*8+j (k>=18 -> 0)
        bf8 bfrag[4];
        float b1c[4];
#pragma unroll
        for (int t = 0; t < 4; t++) {
#pragma unroll
            for (int j = 0; j < 8; j++) {
                int k = grp * 8 + j;
                float wv = (k < DT) ? t_w1[k * H + t * 16 + col] : 0.0f;
                bfrag[t][j] = (short)f2bf(wv);
            }
            b1c[t] = t_b1[t * 16 + col];
        }
        float lg[DT], lb[DT];
#pragma unroll
        for (int i = 0; i < DT; i++) { lg[i] = t_ln_g[i]; lb[i] = t_ln_b[i]; }

        float colsum[4] = {0.0f, 0.0f, 0.0f, 0.0f};

#pragma unroll 1
        for (int tile = 0; tile < 4; tile++) {
            // own row (72B stride, float2-aligned), LN in registers
            const float* rp = xt + (base + tile * 256 + tid) * DT;
            float xv[DT];
#pragma unroll
            for (int q = 0; q < 9; q++) {
                float2 v = *(const float2*)(rp + 2 * q);
                xv[2 * q] = v.x; xv[2 * q + 1] = v.y;
            }
            float mu = 0.0f;
#pragma unroll
            for (int i = 0; i < DT; i++) mu += xv[i];
            mu *= (1.0f / DT);
            float var = 0.0f;
#pragma unroll
            for (int i = 0; i < DT; i++) { float d = xv[i] - mu; var += d * d; }
            var *= (1.0f / DT);
            float rs = rsqrtf(var + 1e-5f);
            unsigned int pk[16];
#pragma unroll
            for (int q = 0; q < 9; q++) {
                float a0 = (xv[2 * q]     - mu) * rs * lg[2 * q]     + lb[2 * q];
                float a1 = (xv[2 * q + 1] - mu) * rs * lg[2 * q + 1] + lb[2 * q + 1];
                pk[q] = (unsigned int)f2bf(a0) | ((unsigned int)f2bf(a1) << 16);
            }
#pragma unroll
            for (int q = 9; q < 16; q++) pk[q] = 0u;   // K-pad 18..31 = 0

            __syncthreads();             // WAR vs previous tile's reads
            {
                uint4* dst = (uint4*)&s_bf[tid * 20];
                dst[0] = make_uint4(pk[0], pk[1], pk[2], pk[3]);
                dst[1] = make_uint4(pk[4], pk[5], pk[6], pk[7]);
                dst[2] = make_uint4(pk[8], pk[9], pk[10], pk[11]);
                dst[3] = make_uint4(pk[12], pk[13], pk[14], pk[15]);
            }
            __syncthreads();             // RAW

            // wave w computes row-sets {w, w+4, w+8, w+12} (16 rows each)
#pragma unroll
            for (int s4 = 0; s4 < 4; s4++) {
                int row = (s4 * 4 + w) * 16 + col;
                bf8 a = *(const bf8*)&s_bf[row * 20 + grp * 4];
#pragma unroll
                for (int t = 0; t < 4; t++) {
                    f32x4 cini = {b1c[t], b1c[t], b1c[t], b1c[t]};
                    f32x4 d = __builtin_amdgcn_mfma_f32_16x16x32_bf16(a, bfrag[t], cini, 0, 0, 0);
                    colsum[t] += (fmaxf(d[0], 0.0f) + fmaxf(d[1], 0.0f))
                               + (fmaxf(d[2], 0.0f) + fmaxf(d[3], 0.0f));
                }
            }
        }

        // reduce colsum across the 4 lane-groups (rows live in grp 0..3)
#pragma unroll
        for (int t = 0; t < 4; t++) {
            colsum[t] += __shfl_xor(colsum[t], 16);
            colsum[t] += __shfl_xor(colsum[t], 32);
        }
        if (lane < 16) {
#pragma unroll
            for (int t = 0; t < 4; t++) s_part[w][t * 16 + lane] = colsum[t];
        }
        __syncthreads();
        if (tid < 64) {
            float s = s_part[0][tid] + s_part[1][tid] + s_part[2][tid] + s_part[3][tid];
            t_sum_partial[bid * 64 + tid] = s;
        }
        if (tid == 0) t_cnt_partial[bid] = 1024.0f;

    } else if (bid < 576) {
        // ---------------- machines part ----------------
        int mbid = bid - 512;
        if (mbid == 0 && tid < 64) mh_contrib[(long)NM * H + tid] = 0.0f;

        float w1r[DM];
#pragma unroll
        for (int i = 0; i < DM; i++) w1r[i] = m_w1[i * H + lane];
        float w2r[H];
#pragma unroll
        for (int i = 0; i < H; i++) w2r[i] = m_w2[i * H + lane];
        float Cr[H];
#pragma unroll
        for (int i = 0; i < H; i++) Cr[i] = lg_w1[(2 * H + i) * H + lane];
        float b1 = m_b1[lane], b2 = m_b2[lane];
        float g0[DM], bb[DM];
#pragma unroll
        for (int i = 0; i < DM; i++) { g0[i] = m_ln_g[i]; bb[i] = m_ln_b[i]; }

        int W = mbid * 4 + w;
        for (int k = 0; k < 8; k++) {
            int m = W * 8 + k;
            float x[DM];
#pragma unroll
            for (int i = 0; i < DM; i++) x[i] = xm[m * DM + i];
            float mu = 0.0f;
#pragma unroll
            for (int i = 0; i < DM; i++) mu += x[i];
            mu *= (1.0f / DM);
            float var = 0.0f;
#pragma unroll
            for (int i = 0; i < DM; i++) { float d = x[i] - mu; var += d * d; }
            var *= (1.0f / DM);
            float rs = rsqrtf(var + 1e-5f);
            float h = b1;
#pragma unroll
            for (int i = 0; i < DM; i++) {
                float xn = (x[i] - mu) * rs * g0[i] + bb[i];
                h = fmaf(xn, w1r[i], h);
            }
            h = fmaxf(h, 0.0f);
            __syncthreads();
            s_h[w][lane] = h;
            __syncthreads();
            float o = b2;
#pragma unroll
            for (int i = 0; i < H; i++) o = fmaf(s_h[w][i], w2r[i], o);
            __syncthreads();
            s_m[w][lane] = o;
            __syncthreads();
            float c = 0.0f;
#pragma unroll
            for (int i = 0; i < H; i++) c = fmaf(s_m[w][i], Cr[i], c);
            mh[(long)m * H + lane] = o;
            mh_contrib[(long)m * H + lane] = c;
        }
    } else {
        // ---------------- fold part ----------------
        int i = bid - 576, j = tid;
        if (j < 64) {
            float a = 0.0f, b = 0.0f;
            for (int k = 0; k < H; k++) {
                a = fmaf(t_w2[i * H + k],  lg_w1[k * H + j], a);
                b = fmaf(lg_w2[i * H + k], o_w1[k * H + j], b);
            }
            W_comb[i * H + j] = a;
            W2comb[i * H + j] = b;
            if (i == 0) {
                float ba = lg_b1[j], b2v = o_b1[j];
                for (int k = 0; k < H; k++) {
                    ba  = fmaf(t_b2[k],  lg_w1[k * H + j], ba);
                    b2v = fmaf(lg_b2[k], o_w1[k * H + j], b2v);
                }
                biasA[j] = ba;
                bias2[j] = b2v;
            }
        }
    }
}

// ---------------------------------------------------------------------------
// K3: per-graph aggregation.  64 blocks (one per graph) x 64 threads.
// ---------------------------------------------------------------------------
__global__ __launch_bounds__(64) void k_graph(
    const float* __restrict__ t_sum_partial, const float* __restrict__ t_cnt_partial,
    const float* __restrict__ mh, const int* __restrict__ mbatch,
    const float* __restrict__ t_w2, const float* __restrict__ t_b2,
    const float* __restrict__ a_w1, const float* __restrict__ a_b1,
    const float* __restrict__ a_w2, const float* __restrict__ a_b2,
    const float* __restrict__ lg_w1, const float* __restrict__ biasA,
    float* __restrict__ aggr_contrib, int* __restrict__ cum)
{
    int g = blockIdx.x, j = threadIdx.x;
    __shared__ float rs_[64], tm[64], mm[64], ah[64], ag[64];
    __shared__ float s_tcnt;
    __shared__ int s_lt[64], s_eq[64];

    float s = 0.0f;
    for (int p = 0; p < 8; p++) s += t_sum_partial[(g * 8 + p) * 64 + j];
    rs_[j] = s;
    if (j == 0) {
        float c = 0.0f;
        for (int p = 0; p < 8; p++) c += t_cnt_partial[g * 8 + p];
        s_tcnt = c;
    }
    int clt = 0, ceq = 0;
    for (int k = 0; k < 32; k++) {
        int bt = mbatch[j * 32 + k];
        clt += (bt < g) ? 1 : 0;
        ceq += (bt == g) ? 1 : 0;
    }
    s_lt[j] = clt; s_eq[j] = ceq;
    float msum = 0.0f;
    for (int k = 0; k < MPG; k++) msum += mh[(long)(g * MPG + k) * H + j];
    __syncthreads();

    int cum_g = 0, mcnt = 0;
    for (int k = 0; k < 64; k++) { cum_g += s_lt[k]; mcnt += s_eq[k]; }
    if (j == 0) cum[g] = cum_g;

    float tcnt = s_tcnt;
    float dot = 0.0f;
    for (int i = 0; i < H; i++) dot = fmaf(rs_[i], t_w2[i * H + j], dot);
    tm[j] = (dot + tcnt * t_b2[j]) / fmaxf(tcnt, 1.0f);
    mm[j] = msum / fmaxf((float)mcnt, 1.0f);
    __syncthreads();

    float h = a_b1[j];
    for (int i = 0; i < H; i++) h = fmaf(tm[i], a_w1[i * H + j], h);
    for (int i = 0; i < H; i++) h = fmaf(mm[i], a_w1[(H + i) * H + j], h);
    ah[j] = fmaxf(h, 0.0f);
    __syncthreads();

    float o = a_b2[j];
    for (int i = 0; i < H; i++) o = fmaf(ah[i], a_w2[i * H + j], o);
    ag[j] = o;
    __syncthreads();

    float c = biasA[j];
    for (int i = 0; i < H; i++) c = fmaf(ag[i], lg_w1[(H + i) * H + j], c);
    aggr_contrib[g * H + j] = c;
}

// ---------------------------------------------------------------------------
// K4 v3: per-label fused head (unchanged from round 5).
// ---------------------------------------------------------------------------
__global__ __launch_bounds__(512) void k_labels3(
    const float* __restrict__ xt, const int* __restrict__ tbatch,
    const int* __restrict__ lidx,
    const float* __restrict__ t_ln_g, const float* __restrict__ t_ln_b,
    const float* __restrict__ t_w1, const float* __restrict__ t_b1,
    const float* __restrict__ W_comb, const float* __restrict__ W2comb,
    const float* __restrict__ bias2,
    const float* __restrict__ o_w2, const float* __restrict__ o_b2,
    const float* __restrict__ aggr_contrib, const float* __restrict__ mh_contrib,
    const int* __restrict__ cum,
    float* __restrict__ out)
{
    __shared__ float s_act[H * 128];      // 32 KB [dim][label]
    __shared__ float s_w1[DT * H];        // 4.5 KB
    __shared__ float s_Wc[H * H];         // 16 KB
    __shared__ float s_W2[H * H];         // 16 KB
    __shared__ float s_b1v[H], s_b2v[H], s_ow2[H];
    __shared__ float s_lng[DT], s_lnb[DT];
    __shared__ int   s_gi[128], s_mi[128], s_t[128];
    __shared__ float s_ob2v;

    int tid = threadIdx.x, lane = tid & 63, w = tid >> 6;   // w in 0..7
    int wb = w * 8;

    for (int i = tid; i < DT * H; i += 512) s_w1[i] = t_w1[i];
    for (int i = tid; i < H * H; i += 512) { s_Wc[i] = W_comb[i]; s_W2[i] = W2comb[i]; }
    if (tid < H) { s_b1v[tid] = t_b1[tid]; s_b2v[tid] = bias2[tid]; s_ow2[tid] = o_w2[tid]; }
    if (tid < DT) { s_lng[tid] = t_ln_g[tid]; s_lnb[tid] = t_ln_b[tid]; }
    if (tid == 0) s_ob2v = o_b2[0];
    if (tid < 128) {
        int t = lidx[blockIdx.x * 128 + tid];
        s_t[tid] = t;
        int g = tbatch[t];
        int assign = (int)xt[(long)t * DT];
        s_gi[tid] = g;
        s_mi[tid] = (assign < 0) ? NM : (assign + cum[g]);
    }
    __syncthreads();

    if (tid < 256) {
        int r = tid >> 1, hh = tid & 1;
        const float* src = xt + (long)s_t[r] * DT + hh * 9;
#pragma unroll
        for (int j = 0; j < 9; j++) s_act[(hh * 9 + j) * 128 + r] = src[j];
    }
    __syncthreads();

    if (tid < 128) {
        float xv[DT];
#pragma unroll
        for (int i = 0; i < DT; i++) xv[i] = s_act[i * 128 + tid];
        float mu = 0.0f;
#pragma unroll
        for (int i = 0; i < DT; i++) mu += xv[i];
        mu *= (1.0f / DT);
        float var = 0.0f;
#pragma unroll
        for (int i = 0; i < DT; i++) { float d = xv[i] - mu; var += d * d; }
        var *= (1.0f / DT);
        float rs = rsqrtf(var + 1e-5f);
#pragma unroll
        for (int i = 0; i < DT; i++)
            s_act[i * 128 + tid] = (xv[i] - mu) * rs * s_lng[i] + s_lnb[i];
    }
    __syncthreads();

    float acc0[8], acc1[8];

#pragma unroll
    for (int k = 0; k < 8; k++) { acc0[k] = s_b1v[wb + k]; acc1[k] = acc0[k]; }
    for (int i = 0; i < DT; i++) {
        float av0 = s_act[i * 128 + lane];
        float av1 = s_act[i * 128 + 64 + lane];
        const float4* wp = (const float4*)(s_w1 + i * H + wb);
        float4 wA = wp[0], wB = wp[1];
        acc0[0] = fmaf(av0, wA.x, acc0[0]); acc1[0] = fmaf(av1, wA.x, acc1[0]);
        acc0[1] = fmaf(av0, wA.y, acc0[1]); acc1[1] = fmaf(av1, wA.y, acc1[1]);
        acc0[2] = fmaf(av0, wA.z, acc0[2]); acc1[2] = fmaf(av1, wA.z, acc1[2]);
        acc0[3] = fmaf(av0, wA.w, acc0[3]); acc1[3] = fmaf(av1, wA.w, acc1[3]);
        acc0[4] = fmaf(av0, wB.x, acc0[4]); acc1[4] = fmaf(av1, wB.x, acc1[4]);
        acc0[5] = fmaf(av0, wB.y, acc0[5]); acc1[5] = fmaf(av1, wB.y, acc1[5]);
        acc0[6] = fmaf(av0, wB.z, acc0[6]); acc1[6] = fmaf(av1, wB.z, acc1[6]);
        acc0[7] = fmaf(av0, wB.w, acc0[7]); acc1[7] = fmaf(av1, wB.w, acc1[7]);
    }
    __syncthreads();
#pragma unroll
    for (int k = 0; k < 8; k++) {
        s_act[(wb + k) * 128 + lane]      = fmaxf(acc0[k], 0.0f);
        s_act[(wb + k) * 128 + 64 + lane] = fmaxf(acc1[k], 0.0f);
    }
    __syncthreads();

    {
        int g0 = s_gi[lane],      m0 = s_mi[lane];
        int g1 = s_gi[64 + lane], m1 = s_mi[64 + lane];
        const float4* a0p = (const float4*)(aggr_contrib + g0 * H + wb);
        const float4* m0p = (const float4*)(mh_contrib + (long)m0 * H + wb);
        const float4* a1p = (const float4*)(aggr_contrib + g1 * H + wb);
        const float4* m1p = (const float4*)(mh_contrib + (long)m1 * H + wb);
        float4 aA = a0p[0], aB = a0p[1], mA = m0p[0], mB = m0p[1];
        float4 cA = a1p[0], cB = a1p[1], nA = m1p[0], nB = m1p[1];
        acc0[0] = aA.x + mA.x; acc0[1] = aA.y + mA.y; acc0[2] = aA.z + mA.z; acc0[3] = aA.w + mA.w;
        acc0[4] = aB.x + mB.x; acc0[5] = aB.y + mB.y; acc0[6] = aB.z + mB.z; acc0[7] = aB.w + mB.w;
        acc1[0] = cA.x + nA.x; acc1[1] = cA.y + nA.y; acc1[2] = cA.z + nA.z; acc1[3] = cA.w + nA.w;
        acc1[4] = cB.x + nB.x; acc1[5] = cB.y + nB.y; acc1[6] = cB.z + nB.z; acc1[7] = cB.w + nB.w;
    }
    for (int i = 0; i < H; i++) {
        float av0 = s_act[i * 128 + lane];
        float av1 = s_act[i * 128 + 64 + lane];
        const float4* wp = (const float4*)(s_Wc + i * H + wb);
        float4 wA = wp[0], wB = wp[1];
        acc0[0] = fmaf(av0, wA.x, acc0[0]); acc1[0] = fmaf(av1, wA.x, acc1[0]);
        acc0[1] = fmaf(av0, wA.y, acc0[1]); acc1[1] = fmaf(av1, wA.y, acc1[1]);
        acc0[2] = fmaf(av0, wA.z, acc0[2]); acc1[2] = fmaf(av1, wA.z, acc1[2]);
        acc0[3] = fmaf(av0, wA.w, acc0[3]); acc1[3] = fmaf(av1, wA.w, acc1[3]);
        acc0[4] = fmaf(av0, wB.x, acc0[4]); acc1[4] = fmaf(av1, wB.x, acc1[4]);
        acc0[5] = fmaf(av0, wB.y, acc0[5]); acc1[5] = fmaf(av1, wB.y, acc1[5]);
        acc0[6] = fmaf(av0, wB.z, acc0[6]); acc1[6] = fmaf(av1, wB.z, acc1[6]);
        acc0[7] = fmaf(av0, wB.w, acc0[7]); acc1[7] = fmaf(av1, wB.w, acc1[7]);
    }
    __syncthreads();
#pragma unroll
    for (int k = 0; k < 8; k++) {
        s_act[(wb + k) * 128 + lane]      = fmaxf(acc0[k], 0.0f);
        s_act[(wb + k) * 128 + 64 + lane] = fmaxf(acc1[k], 0.0f);
    }
    __syncthreads();

#pragma unroll
    for (int k = 0; k < 8; k++) { acc0[k] = s_b2v[wb + k]; acc1[k] = acc0[k]; }
    for (int i = 0; i < H; i++) {
        float av0 = s_act[i * 128 + lane];
        float av1 = s_act[i * 128 + 64 + lane];
        const float4* wp = (const float4*)(s_W2 + i * H + wb);
        float4 wA = wp[0], wB = wp[1];
        acc0[0] = fmaf(av0, wA.x, acc0[0]); acc1[0] = fmaf(av1, wA.x, acc1[0]);
        acc0[1] = fmaf(av0, wA.y, acc0[1]); acc1[1] = fmaf(av1, wA.y, acc1[1]);
        acc0[2] = fmaf(av0, wA.z, acc0[2]); acc1[2] = fmaf(av1, wA.z, acc1[2]);
        acc0[3] = fmaf(av0, wA.w, acc0[3]); acc1[3] = fmaf(av1, wA.w, acc1[3]);
        acc0[4] = fmaf(av0, wB.x, acc0[4]); acc1[4] = fmaf(av1, wB.x, acc1[4]);
        acc0[5] = fmaf(av0, wB.y, acc0[5]); acc1[5] = fmaf(av1, wB.y, acc1[5]);
        acc0[6] = fmaf(av0, wB.z, acc0[6]); acc1[6] = fmaf(av1, wB.z, acc1[6]);
        acc0[7] = fmaf(av0, wB.w, acc0[7]); acc1[7] = fmaf(av1, wB.w, acc1[7]);
    }

    float r0 = 0.0f, r1 = 0.0f;
#pragma unroll
    for (int k = 0; k < 8; k++) {
        float wv2 = s_ow2[wb + k];
        r0 = fmaf(fmaxf(acc0[k], 0.0f), wv2, r0);
        r1 = fmaf(fmaxf(acc1[k], 0.0f), wv2, r1);
    }
    __syncthreads();
    s_act[w * 128 + lane]      = r0;
    s_act[w * 128 + 64 + lane] = r1;
    __syncthreads();
    if (tid < 128) {
        float s = s_ob2v;
#pragma unroll
        for (int q = 0; q < 8; q++) s += s_act[q * 128 + tid];
        out[blockIdx.x * 128 + tid] = s;
    }
}

// ---------------------------------------------------------------------------
extern "C" void kernel_launch(void* const* d_in, const int* in_sizes, int n_in,
                              void* d_out, int out_size, void* d_ws, size_t ws_size,
                              hipStream_t stream)
{
    (void)n_in; (void)out_size; (void)ws_size;
    const float* x_tasks         = (const float*)d_in[0];
    const float* x_machines      = (const float*)d_in[1];
    const int*   x_tasks_batch   = (const int*)d_in[2];
    const int*   x_machines_batch= (const int*)d_in[3];
    const int*   task_label_idx  = (const int*)d_in[4];
    const float* t_ln_g = (const float*)d_in[5];
    const float* t_ln_b = (const float*)d_in[6];
    const float *m_ln_g, *m_ln_b, *t_w1, *t_b1, *t_w2, *t_b2;
    if (in_sizes[7] == DM) {
        m_ln_g = (const float*)d_in[7];  m_ln_b = (const float*)d_in[8];
        t_w1   = (const float*)d_in[9];  t_b1   = (const float*)d_in[10];
        t_w2   = (const float*)d_in[11]; t_b2   = (const float*)d_in[12];
    } else {
        t_w1   = (const float*)d_in[7];  t_b1   = (const float*)d_in[8];
        t_w2   = (const float*)d_in[9];  t_b2   = (const float*)d_in[10];
        m_ln_g = (const float*)d_in[11]; m_ln_b = (const float*)d_in[12];
    }
    const float* m_w1 = (const float*)d_in[13]; const float* m_b1 = (const float*)d_in[14];
    const float* m_w2 = (const float*)d_in[15]; const float* m_b2 = (const float*)d_in[16];
    const float* a_w1 = (const float*)d_in[17]; const float* a_b1 = (const float*)d_in[18];
    const float* a_w2 = (const float*)d_in[19]; const float* a_b2 = (const float*)d_in[20];
    const float* lg_w1= (const float*)d_in[21]; const float* lg_b1= (const float*)d_in[22];
    const float* lg_w2= (const float*)d_in[23]; const float* lg_b2= (const float*)d_in[24];
    const float* o_w1 = (const float*)d_in[25]; const float* o_b1 = (const float*)d_in[26];
    const float* o_w2 = (const float*)d_in[27]; const float* o_b2 = (const float*)d_in[28];

    float* ws = (float*)d_ws;
    float* mh_contrib    = ws;                  // 2049*64 = 131136
    float* mh_arr        = ws + 131136;         // 2048*64 = 131072
    float* t_sum_partial = ws + 262208;         // 512*64  = 32768
    float* t_cnt_partial = ws + 294976;         // 512
    float* W_comb        = ws + 295488;         // 4096
    float* W2comb        = ws + 299584;         // 4096
    float* biasA         = ws + 303680;         // 64
    float* bias2         = ws + 303744;         // 64
    float* aggr_contrib  = ws + 303808;         // 4096
    int*   cum           = (int*)(ws + 307904); // 64

    k_front<<<640, 256, 0, stream>>>(x_tasks, t_ln_g, t_ln_b, t_w1, t_b1,
                                     x_machines, m_ln_g, m_ln_b, m_w1, m_b1, m_w2, m_b2,
                                     lg_w1, t_w2, lg_w2, o_w1, t_b2, lg_b1, lg_b2, o_b1,
                                     t_sum_partial, t_cnt_partial, mh_arr, mh_contrib,
                                     W_comb, W2comb, biasA, bias2);
    k_graph<<<64, 64, 0, stream>>>(t_sum_partial, t_cnt_partial, mh_arr, x_machines_batch,
                                   t_w2, t_b2, a_w1, a_b1, a_w2, a_b2, lg_w1, biasA,
                                   aggr_contrib, cum);
    k_labels3<<<512, 512, 0, stream>>>(x_tasks, x_tasks_batch, task_label_idx,
                                       t_ln_g, t_ln_b, t_w1, t_b1, W_comb, W2comb, bias2,
                                       o_w2, o_b2, aggr_contrib, mh_contrib, cum,
                                       (float*)d_out);
}